// Round 1
// baseline (25542.747 us; speedup 1.0000x reference)
//
#include <hip/hip_runtime.h>
#include <math.h>

#define DIM 128
#define E_NUM 100000
#define P_NUM 800000
#define G_NUM 1000
#define T_STEPS 8
#define R_UNITS 256

__device__ __forceinline__ float selu_f(float x) {
    const float alpha = 1.6732632423543772f;
    const float scale = 1.0507009873554805f;
    return x > 0.f ? scale * x : scale * alpha * expm1f(x);
}

// ---------------------------------------------------------------------------
// Message kernel: for 64 pairs per block, compute
//   msg = selu(concat(h[first], h[second]) @ Wmsg + bmsg)   [64 x 128]
// then atomicAdd rows into agg[second].
// Tiled fp32 GEMM: M=64, N=128, K=256 (chunked by 16). 256 threads,
// each computes a 4x8 register tile.
// ---------------------------------------------------------------------------
#define MT 64
#define KC 16

__global__ __launch_bounds__(256)
void msg_kernel(const float* __restrict__ h, const int* __restrict__ first,
                const int* __restrict__ second, const float* __restrict__ Wmsg,
                const float* __restrict__ bmsg, float* __restrict__ agg)
{
    __shared__ float Xs[MT][KC];
    __shared__ float Ws[KC][DIM];
    __shared__ int f_s[MT], s_s[MT];

    const int tid = threadIdx.x;
    const int p0  = blockIdx.x * MT;

    if (tid < MT) {
        f_s[tid] = first[p0 + tid];
        s_s[tid] = second[p0 + tid];
    }
    __syncthreads();

    const int tx = tid & 15;   // col group: cols tx*8 .. tx*8+7
    const int ty = tid >> 4;   // row group: rows ty*4 .. ty*4+3

    float acc[4][8];
#pragma unroll
    for (int r = 0; r < 4; r++)
#pragma unroll
        for (int c = 0; c < 8; c++) acc[r][c] = 0.f;

    for (int kc = 0; kc < 2 * DIM; kc += KC) {
        // stage X tile (gathered): 64 rows x 16 k. Each thread: one row, 4 k.
        {
            const int row = tid >> 2;
            const int kk  = (tid & 3) * 4;
            const int kg  = kc + kk;
            const int p   = (kg < DIM) ? f_s[row] : s_s[row];
            const int kb  = (kg < DIM) ? kg : (kg - DIM);
            const float4 v = *(const float4*)(h + (size_t)p * DIM + kb);
            *(float4*)(&Xs[row][kk]) = v;
        }
        // stage W tile: 16 rows x 128 cols. Each thread: 8 floats.
        {
            const int i = tid >> 4;
            const int j = (tid & 15) * 8;
            const float4* src = (const float4*)(Wmsg + (size_t)(kc + i) * DIM + j);
            *(float4*)(&Ws[i][j])     = src[0];
            *(float4*)(&Ws[i][j + 4]) = src[1];
        }
        __syncthreads();

#pragma unroll
        for (int kk = 0; kk < KC; kk++) {
            const float a0 = Xs[ty * 4 + 0][kk];
            const float a1 = Xs[ty * 4 + 1][kk];
            const float a2 = Xs[ty * 4 + 2][kk];
            const float a3 = Xs[ty * 4 + 3][kk];
            const float4 b0 = *(const float4*)(&Ws[kk][tx * 8]);
            const float4 b1 = *(const float4*)(&Ws[kk][tx * 8 + 4]);
            const float b[8] = {b0.x, b0.y, b0.z, b0.w, b1.x, b1.y, b1.z, b1.w};
#pragma unroll
            for (int c = 0; c < 8; c++) {
                acc[0][c] += a0 * b[c];
                acc[1][c] += a1 * b[c];
                acc[2][c] += a2 * b[c];
                acc[3][c] += a3 * b[c];
            }
        }
        __syncthreads();
    }

    // epilogue: bias + selu, atomic scatter into agg[second]
    const int colb = tx * 8;
    float bb[8];
#pragma unroll
    for (int c = 0; c < 8; c++) bb[c] = bmsg[colb + c];
#pragma unroll
    for (int r = 0; r < 4; r++) {
        const int row = ty * 4 + r;
        float* dst = agg + (size_t)s_s[row] * DIM + colb;
#pragma unroll
        for (int c = 0; c < 8; c++) {
            atomicAdd(dst + c, selu_f(acc[r][c] + bb[c]));
        }
    }
}

// ---------------------------------------------------------------------------
// GRU kernel (Keras reset_after=True, gate order z,r,h):
//   mx = x@K + b0 ; mh = h@U + b1
//   z = sig(mxz+mhz); r = sig(mxr+mhr); hh = tanh(mxh + r*mhh)
//   h_new = z*h + (1-z)*hh
// 8 edges per block, 128 threads (one per output col), 48 accumulators.
// ---------------------------------------------------------------------------
#define GM 8

__global__ __launch_bounds__(128)
void gru_kernel(const float* __restrict__ agg, const float* __restrict__ h_in,
                float* __restrict__ h_out,
                const float* __restrict__ K, const float* __restrict__ U,
                const float* __restrict__ bias)
{
    __shared__ float Xs[GM][DIM];
    __shared__ float Hs[GM][DIM];
    const int tid = threadIdx.x;        // n in 0..127
    const int e0  = blockIdx.x * GM;

#pragma unroll
    for (int e = 0; e < GM; e++) {
        Xs[e][tid] = agg[(size_t)(e0 + e) * DIM + tid];
        Hs[e][tid] = h_in[(size_t)(e0 + e) * DIM + tid];
    }
    __syncthreads();

    float az[GM], ar[GM], ah[GM], bz[GM], br[GM], bh[GM];
#pragma unroll
    for (int e = 0; e < GM; e++) {
        az[e] = ar[e] = ah[e] = 0.f;
        bz[e] = br[e] = bh[e] = 0.f;
    }

    for (int k = 0; k < DIM; k++) {
        const float wz = K[(size_t)k * 3 * DIM + tid];
        const float wr = K[(size_t)k * 3 * DIM + DIM + tid];
        const float wh = K[(size_t)k * 3 * DIM + 2 * DIM + tid];
        const float uz = U[(size_t)k * 3 * DIM + tid];
        const float ur = U[(size_t)k * 3 * DIM + DIM + tid];
        const float uh = U[(size_t)k * 3 * DIM + 2 * DIM + tid];
#pragma unroll
        for (int e = 0; e < GM; e++) {
            const float x  = Xs[e][k];
            const float hh = Hs[e][k];
            az[e] += x * wz;  ar[e] += x * wr;  ah[e] += x * wh;
            bz[e] += hh * uz; br[e] += hh * ur; bh[e] += hh * uh;
        }
    }

    const float b0z = bias[tid],           b0r = bias[DIM + tid],     b0h = bias[2 * DIM + tid];
    const float b1z = bias[3 * DIM + tid], b1r = bias[4 * DIM + tid], b1h = bias[5 * DIM + tid];

#pragma unroll
    for (int e = 0; e < GM; e++) {
        const float xz = az[e] + b0z, xr = ar[e] + b0r, xh = ah[e] + b0h;
        const float rz = bz[e] + b1z, rr = br[e] + b1r, rh = bh[e] + b1h;
        const float z  = 1.f / (1.f + expf(-(xz + rz)));
        const float r  = 1.f / (1.f + expf(-(xr + rr)));
        const float hc = tanhf(xh + r * rh);
        const float hp = Hs[e][tid];
        h_out[(size_t)(e0 + e) * DIM + tid] = z * hp + (1.f - z) * hc;
    }
}

// ---------------------------------------------------------------------------
// Graph pooling: pooled[gid[e]] += h[e]  (atomic; pooled is 0.5 MB, L2-hot)
// ---------------------------------------------------------------------------
__global__ __launch_bounds__(256)
void pool_kernel(const float* __restrict__ h, const int* __restrict__ gid,
                 float* __restrict__ pooled)
{
    const int idx = blockIdx.x * 256 + threadIdx.x;   // over E*DIM
    const int e = idx >> 7;
    const int n = idx & 127;
    atomicAdd(pooled + (size_t)gid[e] * DIM + n, h[idx]);
}

// ---------------------------------------------------------------------------
// Readout: per-graph block. selu(p@W1+b1) -> selu(@W2+b2) -> @W3+b3
// ---------------------------------------------------------------------------
__global__ __launch_bounds__(256)
void readout_kernel(const float* __restrict__ pooled,
                    const float* __restrict__ W1, const float* __restrict__ b1,
                    const float* __restrict__ W2, const float* __restrict__ b2,
                    const float* __restrict__ W3, const float* __restrict__ b3,
                    float* __restrict__ out)
{
    __shared__ float sp[DIM];
    __shared__ float s1[R_UNITS];
    __shared__ float s2[R_UNITS];
    const int g = blockIdx.x, tid = threadIdx.x;

    if (tid < DIM) sp[tid] = pooled[(size_t)g * DIM + tid];
    __syncthreads();

    float acc = b1[tid];
    for (int k = 0; k < DIM; k++) acc += sp[k] * W1[(size_t)k * R_UNITS + tid];
    s1[tid] = selu_f(acc);
    __syncthreads();

    acc = b2[tid];
    for (int k = 0; k < R_UNITS; k++) acc += s1[k] * W2[(size_t)k * R_UNITS + tid];
    s2[tid] = selu_f(acc) * W3[tid];
    __syncthreads();

    for (int s = 128; s > 0; s >>= 1) {
        if (tid < s) s2[tid] += s2[tid + s];
        __syncthreads();
    }
    if (tid == 0) out[g] = s2[0] + b3[0];
}

// ---------------------------------------------------------------------------
extern "C" void kernel_launch(void* const* d_in, const int* in_sizes, int n_in,
                              void* d_out, int out_size, void* d_ws, size_t ws_size,
                              hipStream_t stream)
{
    const float* link_state = (const float*)d_in[0];
    const int*   gids       = (const int*)d_in[1];
    const int*   first      = (const int*)d_in[2];
    const int*   second     = (const int*)d_in[3];
    // d_in[4] = sates_num_edges (scalar, unused; constants are compile-time)
    const float* Wmsg       = (const float*)d_in[5];
    const float* bmsg       = (const float*)d_in[6];
    const float* gK         = (const float*)d_in[7];
    const float* gU         = (const float*)d_in[8];
    const float* gbias      = (const float*)d_in[9];
    const float* W1         = (const float*)d_in[10];
    const float* b1         = (const float*)d_in[11];
    const float* W2         = (const float*)d_in[12];
    const float* b2         = (const float*)d_in[13];
    const float* W3         = (const float*)d_in[14];
    const float* b3         = (const float*)d_in[15];
    float* out = (float*)d_out;

    // workspace: agg [E,128] | h [E,128]; pooled reuses agg after last step
    float* agg  = (float*)d_ws;
    float* hbuf = agg + (size_t)E_NUM * DIM;

    const size_t agg_bytes = (size_t)E_NUM * DIM * sizeof(float);

    for (int t = 0; t < T_STEPS; t++) {
        const float* hcur = (t == 0) ? link_state : hbuf;
        hipMemsetAsync(agg, 0, agg_bytes, stream);
        msg_kernel<<<P_NUM / MT, 256, 0, stream>>>(hcur, first, second, Wmsg, bmsg, agg);
        gru_kernel<<<E_NUM / GM, 128, 0, stream>>>(agg, hcur, hbuf, gK, gU, gbias);
    }

    float* pooled = agg;  // reuse
    hipMemsetAsync(pooled, 0, (size_t)G_NUM * DIM * sizeof(float), stream);
    pool_kernel<<<(E_NUM * DIM) / 256, 256, 0, stream>>>(hbuf, gids, pooled);
    readout_kernel<<<G_NUM, 256, 0, stream>>>(pooled, W1, b1, W2, b2, W3, b3, out);
}

// Round 2
// 12818.970 us; speedup vs baseline: 1.9926x; 1.9926x over previous
//
#include <hip/hip_runtime.h>
#include <math.h>

#define DIM 128
#define E_NUM 100000
#define P_NUM 800000
#define G_NUM 1000
#define T_STEPS 8
#define R_UNITS 256

__device__ __forceinline__ float selu_f(float x) {
    const float alpha = 1.6732632423543772f;
    const float scale = 1.0507009873554805f;
    return x > 0.f ? scale * x : scale * alpha * expm1f(x);
}

// ===========================================================================
// CSR build (once per launch; states_second fixed across steps)
// ===========================================================================
__global__ __launch_bounds__(256)
void hist_kernel(const int* __restrict__ second, int* __restrict__ counts)
{
    const int p = blockIdx.x * 256 + threadIdx.x;
    atomicAdd(&counts[second[p]], 1);
}

// exclusive scan of counts[0..E-1] -> offsets[0..E]; single block, 1024 thr
__global__ __launch_bounds__(1024)
void scan_kernel(const int* __restrict__ counts, int* __restrict__ offsets)
{
    __shared__ int buf[1024];
    __shared__ int carry_s;
    const int tid = threadIdx.x;
    if (tid == 0) carry_s = 0;
    __syncthreads();
    for (int base = 0; base < E_NUM; base += 1024) {
        const int i = base + tid;
        const int v = (i < E_NUM) ? counts[i] : 0;
        buf[tid] = v;
        __syncthreads();
        for (int off = 1; off < 1024; off <<= 1) {
            const int t = (tid >= off) ? buf[tid - off] : 0;
            __syncthreads();
            buf[tid] += t;
            __syncthreads();
        }
        const int carry = carry_s;
        if (i < E_NUM) offsets[i] = carry + buf[tid] - v;   // exclusive
        __syncthreads();
        if (tid == 0) carry_s += buf[1023];
        __syncthreads();
    }
    if (tid == 0) offsets[E_NUM] = P_NUM;
}

// scatter pairs into destination-sorted order (order within bucket arbitrary)
__global__ __launch_bounds__(256)
void fill_kernel(const int* __restrict__ first, const int* __restrict__ second,
                 const int* __restrict__ offsets, int* __restrict__ cursor,
                 int* __restrict__ sfirst, int* __restrict__ ssecond)
{
    const int p = blockIdx.x * 256 + threadIdx.x;
    const int d = second[p];
    const int pos = atomicAdd(&cursor[d], 1);
    const int idx = offsets[d] + pos;
    sfirst[idx] = first[p];
    ssecond[idx] = d;
}

// ===========================================================================
// Message kernel over destination-sorted pairs:
//   msg = selu(concat(h[first], h[dst]) @ Wmsg + bmsg)   [64 x 128]
// then segmented-sum by dst within the block; plain store for runs fully
// inside the block, atomicAdd only for boundary-straddling runs.
// ===========================================================================
#define MT 64
#define KC 16
#define XPAD 20            // 16B-aligned stride; row groups 2-way bank alias = free

__global__ __launch_bounds__(256)
void msg_seg_kernel(const float* __restrict__ h, const int* __restrict__ sfirst,
                    const int* __restrict__ ssecond, const float* __restrict__ Wmsg,
                    const float* __restrict__ bmsg, float* __restrict__ agg)
{
    __shared__ float Xs[MT][XPAD];
    __shared__ float Ws[KC][DIM];
    __shared__ float Ms[MT][DIM + 1];     // msgs tile; stride 129 -> row walk conflict-free
    __shared__ int f_s[MT], s_s[MT];
    __shared__ int prevdst, nextdst;

    const int tid = threadIdx.x;
    const int p0  = blockIdx.x * MT;

    if (tid < MT) {
        f_s[tid] = sfirst[p0 + tid];
        s_s[tid] = ssecond[p0 + tid];
    }
    if (tid == 64) prevdst = (p0 == 0) ? -1 : ssecond[p0 - 1];
    if (tid == 65) nextdst = (p0 + MT >= P_NUM) ? -1 : ssecond[p0 + MT];
    __syncthreads();

    const int tx = tid & 15;   // cols tx*8 .. +7
    const int ty = tid >> 4;   // rows ty*4 .. +3

    float acc[4][8];
#pragma unroll
    for (int r = 0; r < 4; r++)
#pragma unroll
        for (int c = 0; c < 8; c++) acc[r][c] = 0.f;

    for (int kc = 0; kc < 2 * DIM; kc += KC) {
        {   // stage gathered X tile: 64 rows x 16 k
            const int row = tid >> 2;
            const int kk  = (tid & 3) * 4;
            const int kg  = kc + kk;
            const int p   = (kg < DIM) ? f_s[row] : s_s[row];
            const int kb  = (kg < DIM) ? kg : (kg - DIM);
            const float4 v = *(const float4*)(h + (size_t)p * DIM + kb);
            *(float4*)(&Xs[row][kk]) = v;
        }
        {   // stage W tile: 16 x 128
            const int i = tid >> 4;
            const int j = (tid & 15) * 8;
            const float4* src = (const float4*)(Wmsg + (size_t)(kc + i) * DIM + j);
            *(float4*)(&Ws[i][j])     = src[0];
            *(float4*)(&Ws[i][j + 4]) = src[1];
        }
        __syncthreads();

#pragma unroll
        for (int kk = 0; kk < KC; kk++) {
            const float a0 = Xs[ty * 4 + 0][kk];
            const float a1 = Xs[ty * 4 + 1][kk];
            const float a2 = Xs[ty * 4 + 2][kk];
            const float a3 = Xs[ty * 4 + 3][kk];
            const float4 b0 = *(const float4*)(&Ws[kk][tx * 8]);
            const float4 b1 = *(const float4*)(&Ws[kk][tx * 8 + 4]);
            const float b[8] = {b0.x, b0.y, b0.z, b0.w, b1.x, b1.y, b1.z, b1.w};
#pragma unroll
            for (int c = 0; c < 8; c++) {
                acc[0][c] += a0 * b[c];
                acc[1][c] += a1 * b[c];
                acc[2][c] += a2 * b[c];
                acc[3][c] += a3 * b[c];
            }
        }
        __syncthreads();
    }

    // bias + selu into LDS msgs tile
    const int colb = tx * 8;
    float bb[8];
#pragma unroll
    for (int c = 0; c < 8; c++) bb[c] = bmsg[colb + c];
#pragma unroll
    for (int r = 0; r < 4; r++) {
        const int row = ty * 4 + r;
#pragma unroll
        for (int c = 0; c < 8; c++)
            Ms[row][colb + c] = selu_f(acc[r][c] + bb[c]);
    }
    __syncthreads();

    // segmented reduction: tid -> (row r, col-group cg of 32 cols)
    const int r  = tid & 63;
    const int cg = tid >> 6;
    const int d  = s_s[r];
    const bool leader = (r == 0) || (d != s_s[r - 1]);
    if (leader) {
        int end = r + 1;
        while (end < MT && s_s[end] == d) end++;
        const bool needs_atomic = (r == 0 && d == prevdst) ||
                                  (end == MT && d == nextdst);
        float* dst = agg + (size_t)d * DIM + cg * 32;
        for (int c = 0; c < 32; c++) {
            float s = 0.f;
            for (int rr = r; rr < end; rr++) s += Ms[rr][cg * 32 + c];
            if (needs_atomic) atomicAdd(dst + c, s);
            else              dst[c] = s;
        }
    }
}

// ===========================================================================
// GRU kernel (Keras reset_after=True, gate order z,r,h) — unchanged
// ===========================================================================
#define GM 8

__global__ __launch_bounds__(128)
void gru_kernel(const float* __restrict__ agg, const float* __restrict__ h_in,
                float* __restrict__ h_out,
                const float* __restrict__ K, const float* __restrict__ U,
                const float* __restrict__ bias)
{
    __shared__ float Xs[GM][DIM];
    __shared__ float Hs[GM][DIM];
    const int tid = threadIdx.x;
    const int e0  = blockIdx.x * GM;

#pragma unroll
    for (int e = 0; e < GM; e++) {
        Xs[e][tid] = agg[(size_t)(e0 + e) * DIM + tid];
        Hs[e][tid] = h_in[(size_t)(e0 + e) * DIM + tid];
    }
    __syncthreads();

    float az[GM], ar[GM], ah[GM], bz[GM], br[GM], bh[GM];
#pragma unroll
    for (int e = 0; e < GM; e++) {
        az[e] = ar[e] = ah[e] = 0.f;
        bz[e] = br[e] = bh[e] = 0.f;
    }

    for (int k = 0; k < DIM; k++) {
        const float wz = K[(size_t)k * 3 * DIM + tid];
        const float wr = K[(size_t)k * 3 * DIM + DIM + tid];
        const float wh = K[(size_t)k * 3 * DIM + 2 * DIM + tid];
        const float uz = U[(size_t)k * 3 * DIM + tid];
        const float ur = U[(size_t)k * 3 * DIM + DIM + tid];
        const float uh = U[(size_t)k * 3 * DIM + 2 * DIM + tid];
#pragma unroll
        for (int e = 0; e < GM; e++) {
            const float x  = Xs[e][k];
            const float hh = Hs[e][k];
            az[e] += x * wz;  ar[e] += x * wr;  ah[e] += x * wh;
            bz[e] += hh * uz; br[e] += hh * ur; bh[e] += hh * uh;
        }
    }

    const float b0z = bias[tid],           b0r = bias[DIM + tid],     b0h = bias[2 * DIM + tid];
    const float b1z = bias[3 * DIM + tid], b1r = bias[4 * DIM + tid], b1h = bias[5 * DIM + tid];

#pragma unroll
    for (int e = 0; e < GM; e++) {
        const float xz = az[e] + b0z, xr = ar[e] + b0r, xh = ah[e] + b0h;
        const float rz = bz[e] + b1z, rr = br[e] + b1r, rh = bh[e] + b1h;
        const float z  = 1.f / (1.f + expf(-(xz + rz)));
        const float r  = 1.f / (1.f + expf(-(xr + rr)));
        const float hc = tanhf(xh + r * rh);
        const float hp = Hs[e][tid];
        h_out[(size_t)(e0 + e) * DIM + tid] = z * hp + (1.f - z) * hc;
    }
}

// ===========================================================================
// Graph pooling + readout — unchanged
// ===========================================================================
__global__ __launch_bounds__(256)
void pool_kernel(const float* __restrict__ h, const int* __restrict__ gid,
                 float* __restrict__ pooled)
{
    const int idx = blockIdx.x * 256 + threadIdx.x;
    const int e = idx >> 7;
    const int n = idx & 127;
    atomicAdd(pooled + (size_t)gid[e] * DIM + n, h[idx]);
}

__global__ __launch_bounds__(256)
void readout_kernel(const float* __restrict__ pooled,
                    const float* __restrict__ W1, const float* __restrict__ b1,
                    const float* __restrict__ W2, const float* __restrict__ b2,
                    const float* __restrict__ W3, const float* __restrict__ b3,
                    float* __restrict__ out)
{
    __shared__ float sp[DIM];
    __shared__ float s1[R_UNITS];
    __shared__ float s2[R_UNITS];
    const int g = blockIdx.x, tid = threadIdx.x;

    if (tid < DIM) sp[tid] = pooled[(size_t)g * DIM + tid];
    __syncthreads();

    float acc = b1[tid];
    for (int k = 0; k < DIM; k++) acc += sp[k] * W1[(size_t)k * R_UNITS + tid];
    s1[tid] = selu_f(acc);
    __syncthreads();

    acc = b2[tid];
    for (int k = 0; k < R_UNITS; k++) acc += s1[k] * W2[(size_t)k * R_UNITS + tid];
    s2[tid] = selu_f(acc) * W3[tid];
    __syncthreads();

    for (int s = 128; s > 0; s >>= 1) {
        if (tid < s) s2[tid] += s2[tid + s];
        __syncthreads();
    }
    if (tid == 0) out[g] = s2[0] + b3[0];
}

// ===========================================================================
extern "C" void kernel_launch(void* const* d_in, const int* in_sizes, int n_in,
                              void* d_out, int out_size, void* d_ws, size_t ws_size,
                              hipStream_t stream)
{
    const float* link_state = (const float*)d_in[0];
    const int*   gids       = (const int*)d_in[1];
    const int*   first      = (const int*)d_in[2];
    const int*   second     = (const int*)d_in[3];
    const float* Wmsg       = (const float*)d_in[5];
    const float* bmsg       = (const float*)d_in[6];
    const float* gK         = (const float*)d_in[7];
    const float* gU         = (const float*)d_in[8];
    const float* gbias      = (const float*)d_in[9];
    const float* W1         = (const float*)d_in[10];
    const float* b1         = (const float*)d_in[11];
    const float* W2         = (const float*)d_in[12];
    const float* b2         = (const float*)d_in[13];
    const float* W3         = (const float*)d_in[14];
    const float* b3         = (const float*)d_in[15];
    float* out = (float*)d_out;

    // ws layout (4B words): offsets[100004] | counts[E] | cursor[E] |
    //                       sfirst[P] | ssecond[P] | agg[E*128] | h[E*128]
    int* offsets = (int*)d_ws;
    int* counts  = offsets + 100004;
    int* cursor  = counts + E_NUM;
    int* sfirst  = cursor + E_NUM;
    int* ssecond = sfirst + P_NUM;
    float* agg   = (float*)(ssecond + P_NUM);   // 16B-aligned (8400016 B offset)
    float* hbuf  = agg + (size_t)E_NUM * DIM;

    const size_t agg_bytes = (size_t)E_NUM * DIM * sizeof(float);

    // ---- CSR build (once per launch; inputs fixed across steps) ----
    hipMemsetAsync(counts, 0, E_NUM * sizeof(int), stream);
    hipMemsetAsync(cursor, 0, E_NUM * sizeof(int), stream);
    hist_kernel<<<P_NUM / 256, 256, 0, stream>>>(second, counts);
    scan_kernel<<<1, 1024, 0, stream>>>(counts, offsets);
    fill_kernel<<<P_NUM / 256, 256, 0, stream>>>(first, second, offsets, cursor,
                                                 sfirst, ssecond);

    // ---- message-passing steps ----
    for (int t = 0; t < T_STEPS; t++) {
        const float* hcur = (t == 0) ? link_state : hbuf;
        hipMemsetAsync(agg, 0, agg_bytes, stream);
        msg_seg_kernel<<<P_NUM / MT, 256, 0, stream>>>(hcur, sfirst, ssecond,
                                                       Wmsg, bmsg, agg);
        gru_kernel<<<E_NUM / GM, 128, 0, stream>>>(agg, hcur, hbuf, gK, gU, gbias);
    }

    // ---- pool + readout ----
    float* pooled = agg;  // reuse
    hipMemsetAsync(pooled, 0, (size_t)G_NUM * DIM * sizeof(float), stream);
    pool_kernel<<<(E_NUM * DIM) / 256, 256, 0, stream>>>(hbuf, gids, pooled);
    readout_kernel<<<G_NUM, 256, 0, stream>>>(pooled, W1, b1, W2, b2, W3, b3, out);
}

// Round 4
// 6092.170 us; speedup vs baseline: 4.1927x; 2.1042x over previous
//
#include <hip/hip_runtime.h>
#include <math.h>

#define DIM 128
#define E_NUM 100000
#define P_NUM 800000
#define G_NUM 1000
#define T_STEPS 8
#define R_UNITS 256

typedef __attribute__((ext_vector_type(8))) short bf16x8;   // 8 bf16 = 4 VGPRs
typedef __attribute__((ext_vector_type(4))) float f32x4;    // 16x16 MFMA acc

typedef unsigned short ushort_t;
typedef unsigned int   uint_t;

__device__ __forceinline__ float selu_f(float x) {
    const float alpha = 1.6732632423543772f;
    const float scale = 1.0507009873554805f;
    return x > 0.f ? scale * x : scale * alpha * expm1f(x);
}

__device__ __forceinline__ ushort_t f2bf(float x) {
    uint_t u = __float_as_uint(x);
    uint_t r = (u + 0x7fffu + ((u >> 16) & 1u)) >> 16;
    return (ushort_t)r;
}
__device__ __forceinline__ float bf2f(ushort_t h) {
    return __uint_as_float(((uint_t)h) << 16);
}

// ===========================================================================
// CSR build (once per launch; states_second fixed across steps)
// ===========================================================================
__global__ __launch_bounds__(256)
void hist_kernel(const int* __restrict__ second, int* __restrict__ counts)
{
    const int p = blockIdx.x * 256 + threadIdx.x;
    atomicAdd(&counts[second[p]], 1);
}

__global__ __launch_bounds__(1024)
void scan_kernel(const int* __restrict__ counts, int* __restrict__ offsets)
{
    __shared__ int buf[1024];
    __shared__ int carry_s;
    const int tid = threadIdx.x;
    if (tid == 0) carry_s = 0;
    __syncthreads();
    for (int base = 0; base < E_NUM; base += 1024) {
        const int i = base + tid;
        const int v = (i < E_NUM) ? counts[i] : 0;
        buf[tid] = v;
        __syncthreads();
        for (int off = 1; off < 1024; off <<= 1) {
            const int t = (tid >= off) ? buf[tid - off] : 0;
            __syncthreads();
            buf[tid] += t;
            __syncthreads();
        }
        const int carry = carry_s;
        if (i < E_NUM) offsets[i] = carry + buf[tid] - v;
        __syncthreads();
        if (tid == 0) carry_s += buf[1023];
        __syncthreads();
    }
    if (tid == 0) offsets[E_NUM] = P_NUM;
}

__global__ __launch_bounds__(256)
void fill_kernel(const int* __restrict__ first, const int* __restrict__ second,
                 const int* __restrict__ offsets, int* __restrict__ cursor,
                 int* __restrict__ sfirst, int* __restrict__ ssecond)
{
    const int p = blockIdx.x * 256 + threadIdx.x;
    const int d = second[p];
    const int pos = atomicAdd(&cursor[d], 1);
    const int idx = offsets[d] + pos;
    sfirst[idx] = first[p];
    ssecond[idx] = d;
}

// ===========================================================================
// One-time prep: split-bf16 (hi+lo) of h, and Wmsg packed in 16x16x32 B-frag
// order, hi and lo components.
// wt layout per comp: [kq(4)][ks(2)][nt(8)][lane(64)][8 bf16]
//   B[k][n]: n = nt*16 + (lane&15), k = kq*64 + ks*32 + (lane>>4)*8 + j
// ===========================================================================
__global__ __launch_bounds__(256)
void cast_h_kernel(const float* __restrict__ src,
                   ushort_t* __restrict__ dhi, ushort_t* __restrict__ dlo)
{
    const int idx = blockIdx.x * 256 + threadIdx.x;
    const float x = src[idx];
    const ushort_t hi = f2bf(x);
    dhi[idx] = hi;
    dlo[idx] = f2bf(x - bf2f(hi));
}

__global__ __launch_bounds__(256)
void wt_build_kernel(const float* __restrict__ Wmsg,
                     ushort_t* __restrict__ wt_hi, ushort_t* __restrict__ wt_lo)
{
    const int idx  = blockIdx.x * 256 + threadIdx.x;   // 4096 frag-slots
    const int lane = idx & 63;
    const int nt   = (idx >> 6) & 7;
    const int ks   = (idx >> 9) & 1;
    const int kq   = idx >> 10;
    const int n    = nt * 16 + (lane & 15);
    const int kb   = kq * 64 + ks * 32 + (lane >> 4) * 8;
#pragma unroll
    for (int j = 0; j < 8; j++) {
        const float w = Wmsg[(size_t)(kb + j) * DIM + n];
        const ushort_t hi = f2bf(w);
        wt_hi[(size_t)idx * 8 + j] = hi;
        wt_lo[(size_t)idx * 8 + j] = f2bf(w - bf2f(hi));
    }
}

// ===========================================================================
// bf16x3 MFMA message kernel over destination-sorted pairs.
// Block: 256 thr (4 waves), tile M=64 pairs x N=128, K=256 in 4 phases of 64.
// Wave rt: rows rt*16..+16, all 8 n-tiles (acc = 8 x f32x4).
// A: gathered hi/lo from global in verified 16x16x32 A-frag order.
// B: hi/lo staged 32 KB/phase into LDS. 3 MFMAs per (a,b) tile pair:
//   acc += a_hi*b_hi + a_lo*b_hi + a_hi*b_lo   (lo*lo dropped, ~2^-18)
// Epilogue: bias+selu -> Ms (LDS) -> segmented sum by dst, stores interior,
// atomics only at block-boundary dsts.
// ===========================================================================
#define MT 64
#define MS_STRIDE 132

__global__ __launch_bounds__(256)
void msg_mfma3_kernel(const ushort_t* __restrict__ hbh, const ushort_t* __restrict__ hbl,
                      const int* __restrict__ sfirst, const int* __restrict__ ssecond,
                      const ushort_t* __restrict__ wt_hi, const ushort_t* __restrict__ wt_lo,
                      const float* __restrict__ bmsg, float* __restrict__ agg)
{
    __shared__ __align__(16) char smem_raw[MT * MS_STRIDE * 4];  // 33792 B
    __shared__ int f_s[MT], s_s[MT];
    __shared__ int prevdst, nextdst;

    char*  smemB = smem_raw;          // [comp(2)][ks(2)][nt(8)][lane(64)][16B] = 32 KB
    float* Ms    = (float*)smem_raw;  // epilogue alias (after final barrier)

    const int tid  = threadIdx.x;
    const int lane = tid & 63;
    const int rt   = tid >> 6;        // wave = row-tile (16 rows)
    const int p0   = blockIdx.x * MT;

    if (tid < MT) {
        f_s[tid] = sfirst[p0 + tid];
        s_s[tid] = ssecond[p0 + tid];
    }
    if (tid == 64) prevdst = (p0 == 0) ? -1 : ssecond[p0 - 1];
    if (tid == 65) nextdst = (p0 + MT >= P_NUM) ? -1 : ssecond[p0 + MT];
    __syncthreads();

    const int m16  = lane & 15;
    const int quad = lane >> 4;
    const int rf = f_s[rt * 16 + m16];
    const int rs = s_s[rt * 16 + m16];

    f32x4 acc[8];
#pragma unroll
    for (int nt = 0; nt < 8; nt++) acc[nt] = {};

    for (int kq = 0; kq < 4; kq++) {
        // ---- A gather for this phase (verified frag order) ----
        bf16x8 ah[2], al[2];
#pragma unroll
        for (int ks = 0; ks < 2; ks++) {
            const int kg  = kq * 64 + ks * 32 + quad * 8;
            const int sr  = (kg < DIM) ? rf : rs;
            const int off = kg & (DIM - 1);
            ah[ks] = *(const bf16x8*)(hbh + (size_t)sr * DIM + off);
            al[ks] = *(const bf16x8*)(hbl + (size_t)sr * DIM + off);
        }
        // ---- stage B hi/lo (16 KB each) ----
        {
            const ushort_t* wsrc_h = wt_hi + (size_t)kq * 8192;
            const ushort_t* wsrc_l = wt_lo + (size_t)kq * 8192;
#pragma unroll
            for (int i = 0; i < 4; i++) {
                const int chunk = i * 256 + tid;              // 1024 chunks/comp
                *(uint4*)(smemB + (chunk << 4))         = *(const uint4*)(wsrc_h + (size_t)chunk * 8);
                *(uint4*)(smemB + 16384 + (chunk << 4)) = *(const uint4*)(wsrc_l + (size_t)chunk * 8);
            }
        }
        __syncthreads();

#pragma unroll
        for (int ks = 0; ks < 2; ks++) {
#pragma unroll
            for (int nt = 0; nt < 8; nt++) {
                const bf16x8 bh = *(const bf16x8*)(smemB + ((((ks) * 8 + nt) * 64 + lane) << 4));
                const bf16x8 bl = *(const bf16x8*)(smemB + 16384 + ((((ks) * 8 + nt) * 64 + lane) << 4));
                acc[nt] = __builtin_amdgcn_mfma_f32_16x16x32_bf16(ah[ks], bh, acc[nt], 0, 0, 0);
                acc[nt] = __builtin_amdgcn_mfma_f32_16x16x32_bf16(al[ks], bh, acc[nt], 0, 0, 0);
                acc[nt] = __builtin_amdgcn_mfma_f32_16x16x32_bf16(ah[ks], bl, acc[nt], 0, 0, 0);
            }
        }
        __syncthreads();
    }

    // ---- epilogue: bias + selu into Ms (verified C layout:
    //      col = lane&15, row = quad*4 + reg) ----
#pragma unroll
    for (int nt = 0; nt < 8; nt++) {
        const int c = nt * 16 + m16;
        const float bb = bmsg[c];
#pragma unroll
        for (int reg = 0; reg < 4; reg++) {
            const int row = rt * 16 + quad * 4 + reg;
            Ms[row * MS_STRIDE + c] = selu_f(acc[nt][reg] + bb);
        }
    }
    __syncthreads();

    // ---- segmented reduction by destination ----
    const int r  = tid & 63;
    const int cg = tid >> 6;             // 4 col groups of 32
    const int d  = s_s[r];
    const bool leader = (r == 0) || (d != s_s[r - 1]);
    if (leader) {
        int end = r + 1;
        while (end < MT && s_s[end] == d) end++;
        const bool needs_atomic = (r == 0 && d == prevdst) ||
                                  (end == MT && d == nextdst);
        float sacc[32];
#pragma unroll
        for (int c = 0; c < 32; c++) sacc[c] = 0.f;
        for (int rr = r; rr < end; rr++) {
            const float* mrow = Ms + rr * MS_STRIDE + cg * 32;
#pragma unroll
            for (int c = 0; c < 32; c++) sacc[c] += mrow[c];
        }
        float* dst = agg + (size_t)d * DIM + cg * 32;
        if (needs_atomic) {
#pragma unroll
            for (int c = 0; c < 32; c++) atomicAdd(dst + c, sacc[c]);
        } else {
#pragma unroll
            for (int c4 = 0; c4 < 8; c4++) {
                float4 v = make_float4(sacc[c4 * 4], sacc[c4 * 4 + 1],
                                       sacc[c4 * 4 + 2], sacc[c4 * 4 + 3]);
                *(float4*)(dst + c4 * 4) = v;
            }
        }
    }
}

// ===========================================================================
// GRU kernel (Keras reset_after=True, gate order z,r,h). fp32 math.
// h stored as split-bf16 pair (hi+lo, ~17 mantissa bits); in-place update.
// ===========================================================================
#define GM 16

__global__ __launch_bounds__(128)
void gru_kernel(const float* __restrict__ agg,
                ushort_t* __restrict__ hbh, ushort_t* __restrict__ hbl,
                const float* __restrict__ K, const float* __restrict__ U,
                const float* __restrict__ bias)
{
    __shared__ float Xs[GM][DIM];
    __shared__ float Hs[GM][DIM];
    const int tid = threadIdx.x;
    const int e0  = blockIdx.x * GM;

#pragma unroll
    for (int e = 0; e < GM; e++) {
        const size_t idx = (size_t)(e0 + e) * DIM + tid;
        Xs[e][tid] = agg[idx];
        Hs[e][tid] = bf2f(hbh[idx]) + bf2f(hbl[idx]);
    }
    __syncthreads();

    float az[GM], ar[GM], ah[GM], bz[GM], br[GM], bh[GM];
#pragma unroll
    for (int e = 0; e < GM; e++) {
        az[e] = ar[e] = ah[e] = 0.f;
        bz[e] = br[e] = bh[e] = 0.f;
    }

    for (int k = 0; k < DIM; k++) {
        const float wz = K[(size_t)k * 3 * DIM + tid];
        const float wr = K[(size_t)k * 3 * DIM + DIM + tid];
        const float wh = K[(size_t)k * 3 * DIM + 2 * DIM + tid];
        const float uz = U[(size_t)k * 3 * DIM + tid];
        const float ur = U[(size_t)k * 3 * DIM + DIM + tid];
        const float uh = U[(size_t)k * 3 * DIM + 2 * DIM + tid];
#pragma unroll
        for (int e = 0; e < GM; e++) {
            const float x  = Xs[e][k];
            const float hh = Hs[e][k];
            az[e] += x * wz;  ar[e] += x * wr;  ah[e] += x * wh;
            bz[e] += hh * uz; br[e] += hh * ur; bh[e] += hh * uh;
        }
    }

    const float b0z = bias[tid],           b0r = bias[DIM + tid],     b0h = bias[2 * DIM + tid];
    const float b1z = bias[3 * DIM + tid], b1r = bias[4 * DIM + tid], b1h = bias[5 * DIM + tid];

#pragma unroll
    for (int e = 0; e < GM; e++) {
        const float xz = az[e] + b0z, xr = ar[e] + b0r, xh = ah[e] + b0h;
        const float rz = bz[e] + b1z, rr = br[e] + b1r, rh = bh[e] + b1h;
        const float z  = 1.f / (1.f + expf(-(xz + rz)));
        const float r  = 1.f / (1.f + expf(-(xr + rr)));
        const float hc = tanhf(xh + r * rh);
        const float hp = Hs[e][tid];
        const float hn = z * hp + (1.f - z) * hc;
        const size_t idx = (size_t)(e0 + e) * DIM + tid;
        const ushort_t hi = f2bf(hn);
        hbh[idx] = hi;
        hbl[idx] = f2bf(hn - bf2f(hi));
    }
}

// ===========================================================================
// Graph pooling + readout
// ===========================================================================
__global__ __launch_bounds__(256)
void pool_kernel(const ushort_t* __restrict__ hbh, const ushort_t* __restrict__ hbl,
                 const int* __restrict__ gid, float* __restrict__ pooled)
{
    const int idx = blockIdx.x * 256 + threadIdx.x;
    const int e = idx >> 7;
    const int n = idx & 127;
    const float hv = bf2f(hbh[idx]) + bf2f(hbl[idx]);
    atomicAdd(pooled + (size_t)gid[e] * DIM + n, hv);
}

__global__ __launch_bounds__(256)
void readout_kernel(const float* __restrict__ pooled,
                    const float* __restrict__ W1, const float* __restrict__ b1,
                    const float* __restrict__ W2, const float* __restrict__ b2,
                    const float* __restrict__ W3, const float* __restrict__ b3,
                    float* __restrict__ out)
{
    __shared__ float sp[DIM];
    __shared__ float s1[R_UNITS];
    __shared__ float s2[R_UNITS];
    const int g = blockIdx.x, tid = threadIdx.x;

    if (tid < DIM) sp[tid] = pooled[(size_t)g * DIM + tid];
    __syncthreads();

    float acc = b1[tid];
    for (int k = 0; k < DIM; k++) acc += sp[k] * W1[(size_t)k * R_UNITS + tid];
    s1[tid] = selu_f(acc);
    __syncthreads();

    acc = b2[tid];
    for (int k = 0; k < R_UNITS; k++) acc += s1[k] * W2[(size_t)k * R_UNITS + tid];
    s2[tid] = selu_f(acc) * W3[tid];
    __syncthreads();

    for (int s = 128; s > 0; s >>= 1) {
        if (tid < s) s2[tid] += s2[tid + s];
        __syncthreads();
    }
    if (tid == 0) out[g] = s2[0] + b3[0];
}

// ===========================================================================
extern "C" void kernel_launch(void* const* d_in, const int* in_sizes, int n_in,
                              void* d_out, int out_size, void* d_ws, size_t ws_size,
                              hipStream_t stream)
{
    const float* link_state = (const float*)d_in[0];
    const int*   gids       = (const int*)d_in[1];
    const int*   first      = (const int*)d_in[2];
    const int*   second     = (const int*)d_in[3];
    const float* Wmsg       = (const float*)d_in[5];
    const float* bmsg       = (const float*)d_in[6];
    const float* gK         = (const float*)d_in[7];
    const float* gU         = (const float*)d_in[8];
    const float* gbias      = (const float*)d_in[9];
    const float* W1         = (const float*)d_in[10];
    const float* b1         = (const float*)d_in[11];
    const float* W2         = (const float*)d_in[12];
    const float* b2         = (const float*)d_in[13];
    const float* W3         = (const float*)d_in[14];
    const float* b3         = (const float*)d_in[15];
    float* out = (float*)d_out;

    // ws layout (byte offsets, all 16B-aligned):
    //   offsets[100004] counts[1e5] cursor[1e5] sfirst[P] ssecond[P]
    //   wt_hi[32768 us] wt_lo[32768 us] hb_hi[E*128 us] hb_lo[E*128 us]
    //   agg[E*128 f32]                                   (~135.7 MB total)
    int* offsets = (int*)d_ws;
    int* counts  = offsets + 100004;
    int* cursor  = counts + E_NUM;
    int* sfirst  = cursor + E_NUM;
    int* ssecond = sfirst + P_NUM;
    ushort_t* wt_hi = (ushort_t*)(ssecond + P_NUM);        // 7,665,552... see math
    ushort_t* wt_lo = wt_hi + 32768;
    ushort_t* hb_hi = wt_lo + 32768;
    ushort_t* hb_lo = hb_hi + (size_t)E_NUM * DIM;
    float*    agg   = (float*)(hb_lo + (size_t)E_NUM * DIM);

    const size_t agg_bytes = (size_t)E_NUM * DIM * sizeof(float);

    // ---- one-time prep ----
    hipMemsetAsync(counts, 0, E_NUM * sizeof(int), stream);
    hipMemsetAsync(cursor, 0, E_NUM * sizeof(int), stream);
    hist_kernel<<<P_NUM / 256, 256, 0, stream>>>(second, counts);
    scan_kernel<<<1, 1024, 0, stream>>>(counts, offsets);
    fill_kernel<<<P_NUM / 256, 256, 0, stream>>>(first, second, offsets, cursor,
                                                 sfirst, ssecond);
    wt_build_kernel<<<16, 256, 0, stream>>>(Wmsg, wt_hi, wt_lo);
    cast_h_kernel<<<(E_NUM * DIM) / 256, 256, 0, stream>>>(link_state, hb_hi, hb_lo);

    // ---- message-passing steps ----
    for (int t = 0; t < T_STEPS; t++) {
        hipMemsetAsync(agg, 0, agg_bytes, stream);
        msg_mfma3_kernel<<<P_NUM / MT, 256, 0, stream>>>(hb_hi, hb_lo,
                                                         sfirst, ssecond,
                                                         wt_hi, wt_lo, bmsg, agg);
        gru_kernel<<<E_NUM / GM, 128, 0, stream>>>(agg, hb_hi, hb_lo,
                                                   gK, gU, gbias);
    }

    // ---- pool + readout ----
    float* pooled = agg;  // reuse
    hipMemsetAsync(pooled, 0, (size_t)G_NUM * DIM * sizeof(float), stream);
    pool_kernel<<<(E_NUM * DIM) / 256, 256, 0, stream>>>(hb_hi, hb_lo, gids, pooled);
    readout_kernel<<<G_NUM, 256, 0, stream>>>(pooled, W1, b1, W2, b2, W3, b3, out);
}

// Round 5
// 6080.898 us; speedup vs baseline: 4.2005x; 1.0019x over previous
//
#include <hip/hip_runtime.h>
#include <math.h>

#define DIM 128
#define E_NUM 100000
#define P_NUM 800000
#define G_NUM 1000
#define T_STEPS 8
#define R_UNITS 256

typedef __attribute__((ext_vector_type(8))) short bf16x8;   // 8 bf16 = 4 VGPRs
typedef __attribute__((ext_vector_type(4))) float f32x4;    // 16x16 MFMA acc

typedef unsigned short ushort_t;
typedef unsigned int   uint_t;

__device__ __forceinline__ float selu_f(float x) {
    const float alpha = 1.6732632423543772f;
    const float scale = 1.0507009873554805f;
    return x > 0.f ? scale * x : scale * alpha * expm1f(x);
}

__device__ __forceinline__ ushort_t f2bf(float x) {
    uint_t u = __float_as_uint(x);
    uint_t r = (u + 0x7fffu + ((u >> 16) & 1u)) >> 16;
    return (ushort_t)r;
}
__device__ __forceinline__ float bf2f(ushort_t h) {
    return __uint_as_float(((uint_t)h) << 16);
}

// ===========================================================================
// CSR build (once per launch; states_second fixed across steps)
// ===========================================================================
__global__ __launch_bounds__(256)
void hist_kernel(const int* __restrict__ second, int* __restrict__ counts)
{
    const int p = blockIdx.x * 256 + threadIdx.x;
    atomicAdd(&counts[second[p]], 1);
}

__global__ __launch_bounds__(1024)
void scan_kernel(const int* __restrict__ counts, int* __restrict__ offsets)
{
    __shared__ int buf[1024];
    __shared__ int carry_s;
    const int tid = threadIdx.x;
    if (tid == 0) carry_s = 0;
    __syncthreads();
    for (int base = 0; base < E_NUM; base += 1024) {
        const int i = base + tid;
        const int v = (i < E_NUM) ? counts[i] : 0;
        buf[tid] = v;
        __syncthreads();
        for (int off = 1; off < 1024; off <<= 1) {
            const int t = (tid >= off) ? buf[tid - off] : 0;
            __syncthreads();
            buf[tid] += t;
            __syncthreads();
        }
        const int carry = carry_s;
        if (i < E_NUM) offsets[i] = carry + buf[tid] - v;
        __syncthreads();
        if (tid == 0) carry_s += buf[1023];
        __syncthreads();
    }
    if (tid == 0) offsets[E_NUM] = P_NUM;
}

__global__ __launch_bounds__(256)
void fill_kernel(const int* __restrict__ first, const int* __restrict__ second,
                 const int* __restrict__ offsets, int* __restrict__ cursor,
                 int* __restrict__ sfirst, int* __restrict__ ssecond)
{
    const int p = blockIdx.x * 256 + threadIdx.x;
    const int d = second[p];
    const int pos = atomicAdd(&cursor[d], 1);
    const int idx = offsets[d] + pos;
    sfirst[idx] = first[p];
    ssecond[idx] = d;
}

// ===========================================================================
// One-time prep.
// cast_h: split-bf16 (hi+lo) of link_state.
// wt (msg weights Wmsg [256,128]), frag-packed for DIRECT GLOBAL reads:
//   wt[ks(8)][comp(2)][nt(8)][lane(64)][8 bf16]; B[k][n]:
//   n = nt*16 + (lane&15), k = ks*32 + (lane>>4)*8 + j.   (128 KB, L2-hot)
// wb (GRU weights K,U [128,384] each), same frag scheme over combined N=384:
//   wb[ks(4)][gemm(2)][comp(2)][nt(24)][lane(64)][8 bf16]  (384 KB, L2-hot)
// ===========================================================================
__global__ __launch_bounds__(256)
void cast_h_kernel(const float* __restrict__ src,
                   ushort_t* __restrict__ dhi, ushort_t* __restrict__ dlo)
{
    const int idx = blockIdx.x * 256 + threadIdx.x;
    const float x = src[idx];
    const ushort_t hi = f2bf(x);
    dhi[idx] = hi;
    dlo[idx] = f2bf(x - bf2f(hi));
}

__global__ __launch_bounds__(256)
void wt_build_kernel(const float* __restrict__ Wmsg, ushort_t* __restrict__ wt)
{
    const int idx  = blockIdx.x * 256 + threadIdx.x;   // 8192 frag-slots
    const int lane = idx & 63;
    const int nt   = (idx >> 6) & 7;
    const int comp = (idx >> 9) & 1;
    const int ks   = idx >> 10;                        // 0..7
    const int n    = nt * 16 + (lane & 15);
    const int kb   = ks * 32 + (lane >> 4) * 8;
#pragma unroll
    for (int j = 0; j < 8; j++) {
        const float w = Wmsg[(size_t)(kb + j) * DIM + n];
        const ushort_t hi = f2bf(w);
        wt[(size_t)idx * 8 + j] = comp ? f2bf(w - bf2f(hi)) : hi;
    }
}

__global__ __launch_bounds__(256)
void wb_build_kernel(const float* __restrict__ K, const float* __restrict__ U,
                     ushort_t* __restrict__ wb)
{
    const int idx  = blockIdx.x * 256 + threadIdx.x;   // 24576 frag-slots
    const int lane = idx & 63;
    int t = idx >> 6;                                  // 0..383
    const int nt   = t % 24;  t /= 24;
    const int comp = t & 1;   t >>= 1;
    const int gemm = t & 1;
    const int ks   = t >> 1;                           // 0..3
    const float* src = gemm ? U : K;
    const int n  = nt * 16 + (lane & 15);
    const int kb = ks * 32 + (lane >> 4) * 8;
#pragma unroll
    for (int j = 0; j < 8; j++) {
        const float w = src[(size_t)(kb + j) * 384 + n];
        const ushort_t hi = f2bf(w);
        wb[(size_t)idx * 8 + j] = comp ? f2bf(w - bf2f(hi)) : hi;
    }
}

// ===========================================================================
// bf16x3 MFMA message kernel. Block: 256 thr (4 waves), M=64 pairs, N=128,
// K=256 (8 k-steps of 32). Wave w: ALL 4 row-tiles x 2 n-tiles (disjoint
// across waves -> no B reuse in block -> B read DIRECT from global wt;
// no k-loop LDS, no k-loop barriers). A: gathered hi/lo; per k-step the 4
// quads of a row cover one aligned 64B segment (no overfetch).
// Epilogue: bias+selu -> Ms (LDS) -> segmented sum by dst.
// ===========================================================================
#define MT 64
#define MS_STRIDE 132

__global__ __launch_bounds__(256, 3)
void msg_mfma3_kernel(const ushort_t* __restrict__ hbh, const ushort_t* __restrict__ hbl,
                      const int* __restrict__ sfirst, const int* __restrict__ ssecond,
                      const ushort_t* __restrict__ wt,
                      const float* __restrict__ bmsg, float* __restrict__ agg)
{
    __shared__ float Ms[MT * MS_STRIDE];          // 33792 B
    __shared__ int f_s[MT], s_s[MT];
    __shared__ int prevdst, nextdst;

    const int tid  = threadIdx.x;
    const int lane = tid & 63;
    const int w    = tid >> 6;
    const int p0   = blockIdx.x * MT;

    if (tid < MT) {
        f_s[tid] = sfirst[p0 + tid];
        s_s[tid] = ssecond[p0 + tid];
    }
    if (tid == 64) prevdst = (p0 == 0) ? -1 : ssecond[p0 - 1];
    if (tid == 65) nextdst = (p0 + MT >= P_NUM) ? -1 : ssecond[p0 + MT];
    __syncthreads();

    const int m16  = lane & 15;
    const int quad = lane >> 4;

    int rf[4], rs[4];
#pragma unroll
    for (int rt = 0; rt < 4; rt++) {
        rf[rt] = f_s[rt * 16 + m16];
        rs[rt] = s_s[rt * 16 + m16];
    }

    f32x4 acc[4][2];
#pragma unroll
    for (int rt = 0; rt < 4; rt++)
#pragma unroll
        for (int ntl = 0; ntl < 2; ntl++) acc[rt][ntl] = {};

#pragma unroll 1
    for (int ks = 0; ks < 8; ks++) {
        const int kg  = ks * 32 + quad * 8;        // k-step never straddles 128
        const bool use_f = (kg < DIM);
        const int off = kg & (DIM - 1);
        bf16x8 ah[4], al[4];
#pragma unroll
        for (int rt = 0; rt < 4; rt++) {
            const int row = use_f ? rf[rt] : rs[rt];
            ah[rt] = *(const bf16x8*)(hbh + (size_t)row * DIM + off);
            al[rt] = *(const bf16x8*)(hbl + (size_t)row * DIM + off);
        }
#pragma unroll
        for (int ntl = 0; ntl < 2; ntl++) {
            const int nt = w * 2 + ntl;
            const bf16x8 bh = *(const bf16x8*)(wt + (size_t)(((ks * 2 + 0) * 8 + nt) * 64 + lane) * 8);
            const bf16x8 bl = *(const bf16x8*)(wt + (size_t)(((ks * 2 + 1) * 8 + nt) * 64 + lane) * 8);
#pragma unroll
            for (int rt = 0; rt < 4; rt++) {
                acc[rt][ntl] = __builtin_amdgcn_mfma_f32_16x16x32_bf16(ah[rt], bh, acc[rt][ntl], 0, 0, 0);
                acc[rt][ntl] = __builtin_amdgcn_mfma_f32_16x16x32_bf16(al[rt], bh, acc[rt][ntl], 0, 0, 0);
                acc[rt][ntl] = __builtin_amdgcn_mfma_f32_16x16x32_bf16(ah[rt], bl, acc[rt][ntl], 0, 0, 0);
            }
        }
    }

    // ---- epilogue: bias + selu into Ms (C layout: col=lane&15, row=quad*4+reg) ----
#pragma unroll
    for (int ntl = 0; ntl < 2; ntl++) {
        const int c = (w * 2 + ntl) * 16 + m16;
        const float bb = bmsg[c];
#pragma unroll
        for (int rt = 0; rt < 4; rt++) {
#pragma unroll
            for (int reg = 0; reg < 4; reg++) {
                const int row = rt * 16 + quad * 4 + reg;
                Ms[row * MS_STRIDE + c] = selu_f(acc[rt][ntl][reg] + bb);
            }
        }
    }
    __syncthreads();

    // ---- segmented reduction by destination ----
    const int r  = tid & 63;
    const int cg = tid >> 6;
    const int d  = s_s[r];
    const bool leader = (r == 0) || (d != s_s[r - 1]);
    if (leader) {
        int end = r + 1;
        while (end < MT && s_s[end] == d) end++;
        const bool needs_atomic = (r == 0 && d == prevdst) ||
                                  (end == MT && d == nextdst);
        float sacc[32];
#pragma unroll
        for (int c = 0; c < 32; c++) sacc[c] = 0.f;
        for (int rr = r; rr < end; rr++) {
            const float* mrow = Ms + rr * MS_STRIDE + cg * 32;
#pragma unroll
            for (int c = 0; c < 32; c++) sacc[c] += mrow[c];
        }
        float* dst = agg + (size_t)d * DIM + cg * 32;
        if (needs_atomic) {
#pragma unroll
            for (int c = 0; c < 32; c++) atomicAdd(dst + c, sacc[c]);
        } else {
#pragma unroll
            for (int c4 = 0; c4 < 8; c4++) {
                float4 v = make_float4(sacc[c4 * 4], sacc[c4 * 4 + 1],
                                       sacc[c4 * 4 + 2], sacc[c4 * 4 + 3]);
                *(float4*)(dst + c4 * 4) = v;
            }
        }
    }
}

// ===========================================================================
// bf16x3 MFMA GRU kernel. Block: 256 thr (4 waves), M=32 edges (3125 blocks
// exact). Combined N=384 (z|r|h); wave w owns n-tiles w*6..w*6+5 of BOTH
// gemms (x@K from fp32 agg, inline hi/lo split; h@U from stored hi/lo).
// B direct from global wb (L2-hot, disjoint across waves). K=128, 4 k-steps.
// Epilogue: accs -> LDS exchange (z,r summed; xh,rh separate) -> gates ->
// h written hi/lo in place.
// ===========================================================================
#define EXS 132

__global__ __launch_bounds__(256, 2)
void gru_mfma_kernel(const float* __restrict__ agg,
                     ushort_t* __restrict__ hbh, ushort_t* __restrict__ hbl,
                     const ushort_t* __restrict__ wb,
                     const float* __restrict__ bias)
{
    __shared__ float ex[4 * 32 * EXS];            // 67584 B
    const int tid  = threadIdx.x;
    const int lane = tid & 63;
    const int w    = tid >> 6;
    const int e0   = blockIdx.x * 32;
    const int m16  = lane & 15;
    const int quad = lane >> 4;

    f32x4 ax[2][6], ah[2][6];
#pragma unroll
    for (int rt = 0; rt < 2; rt++)
#pragma unroll
        for (int n = 0; n < 6; n++) { ax[rt][n] = {}; ah[rt][n] = {}; }

#pragma unroll 1
    for (int ks = 0; ks < 4; ks++) {
        const int koff = ks * 32 + quad * 8;
        bf16x8 xh_[2], xl_[2], hh_[2], hl_[2];
#pragma unroll
        for (int rt = 0; rt < 2; rt++) {
            const size_t grow = (size_t)(e0 + rt * 16 + m16);
            const float* xp = agg + grow * DIM + koff;
            const float4 v0 = *(const float4*)xp;
            const float4 v1 = *(const float4*)(xp + 4);
            float xv[8] = {v0.x, v0.y, v0.z, v0.w, v1.x, v1.y, v1.z, v1.w};
            bf16x8 xh_t, xl_t;
#pragma unroll
            for (int j = 0; j < 8; j++) {
                const ushort_t hi = f2bf(xv[j]);
                xh_t[j] = (short)hi;
                xl_t[j] = (short)f2bf(xv[j] - bf2f(hi));
            }
            xh_[rt] = xh_t;
            xl_[rt] = xl_t;
            hh_[rt] = *(const bf16x8*)(hbh + grow * DIM + koff);
            hl_[rt] = *(const bf16x8*)(hbl + grow * DIM + koff);
        }
#pragma unroll
        for (int ntl = 0; ntl < 6; ntl++) {
            const int nt = w * 6 + ntl;
            const size_t base = (size_t)(ks * 2) * 2 * 24;   // [ks][gemm][comp]
            const bf16x8 bKh = *(const bf16x8*)(wb + (((base + 0 * 24) + nt) * 64 + lane) * 8);
            const bf16x8 bKl = *(const bf16x8*)(wb + (((base + 1 * 24) + nt) * 64 + lane) * 8);
            const bf16x8 bUh = *(const bf16x8*)(wb + (((base + 2 * 24) + nt) * 64 + lane) * 8);
            const bf16x8 bUl = *(const bf16x8*)(wb + (((base + 3 * 24) + nt) * 64 + lane) * 8);
#pragma unroll
            for (int rt = 0; rt < 2; rt++) {
                ax[rt][ntl] = __builtin_amdgcn_mfma_f32_16x16x32_bf16(xh_[rt], bKh, ax[rt][ntl], 0, 0, 0);
                ax[rt][ntl] = __builtin_amdgcn_mfma_f32_16x16x32_bf16(xl_[rt], bKh, ax[rt][ntl], 0, 0, 0);
                ax[rt][ntl] = __builtin_amdgcn_mfma_f32_16x16x32_bf16(xh_[rt], bKl, ax[rt][ntl], 0, 0, 0);
                ah[rt][ntl] = __builtin_amdgcn_mfma_f32_16x16x32_bf16(hh_[rt], bUh, ah[rt][ntl], 0, 0, 0);
                ah[rt][ntl] = __builtin_amdgcn_mfma_f32_16x16x32_bf16(hl_[rt], bUh, ah[rt][ntl], 0, 0, 0);
                ah[rt][ntl] = __builtin_amdgcn_mfma_f32_16x16x32_bf16(hh_[rt], bUl, ah[rt][ntl], 0, 0, 0);
            }
        }
    }

    // ---- exchange: planes 0=z-sum, 1=r-sum, 2=xh, 3=rh ----
#pragma unroll
    for (int ntl = 0; ntl < 6; ntl++) {
        const int cglob = (w * 6 + ntl) * 16 + m16;     // 0..383
        const int gb = cglob >> 7;                       // 0=z 1=r 2=h
        const int cb = cglob & 127;
        const float b0v = bias[cglob];
        const float b1v = bias[384 + cglob];
#pragma unroll
        for (int rt = 0; rt < 2; rt++) {
#pragma unroll
            for (int reg = 0; reg < 4; reg++) {
                const int row = rt * 16 + quad * 4 + reg;
                const float mx = ax[rt][ntl][reg] + b0v;
                const float mh = ah[rt][ntl][reg] + b1v;
                if (gb == 0)      ex[0 * 32 * EXS + row * EXS + cb] = mx + mh;
                else if (gb == 1) ex[1 * 32 * EXS + row * EXS + cb] = mx + mh;
                else {
                    ex[2 * 32 * EXS + row * EXS + cb] = mx;
                    ex[3 * 32 * EXS + row * EXS + cb] = mh;
                }
            }
        }
    }
    __syncthreads();

    // ---- gates: thread t -> row t>>3, cols (t&7)*16 .. +15 ----
    const int row = tid >> 3;
    const int c0  = (tid & 7) * 16;
    const size_t gbase = (size_t)(e0 + row) * DIM;
#pragma unroll
    for (int j = 0; j < 16; j++) {
        const int c = c0 + j;
        const float sz = ex[0 * 32 * EXS + row * EXS + c];
        const float sr = ex[1 * 32 * EXS + row * EXS + c];
        const float xh = ex[2 * 32 * EXS + row * EXS + c];
        const float rh = ex[3 * 32 * EXS + row * EXS + c];
        const float z  = 1.f / (1.f + expf(-sz));
        const float r  = 1.f / (1.f + expf(-sr));
        const float hc = tanhf(xh + r * rh);
        const size_t g = gbase + c;
        const float hp = bf2f(hbh[g]) + bf2f(hbl[g]);
        const float hn = z * hp + (1.f - z) * hc;
        const ushort_t hi = f2bf(hn);
        hbh[g] = hi;
        hbl[g] = f2bf(hn - bf2f(hi));
    }
}

// ===========================================================================
// Graph pooling + readout
// ===========================================================================
__global__ __launch_bounds__(256)
void pool_kernel(const ushort_t* __restrict__ hbh, const ushort_t* __restrict__ hbl,
                 const int* __restrict__ gid, float* __restrict__ pooled)
{
    const int idx = blockIdx.x * 256 + threadIdx.x;
    const int e = idx >> 7;
    const int n = idx & 127;
    const float hv = bf2f(hbh[idx]) + bf2f(hbl[idx]);
    atomicAdd(pooled + (size_t)gid[e] * DIM + n, hv);
}

__global__ __launch_bounds__(256)
void readout_kernel(const float* __restrict__ pooled,
                    const float* __restrict__ W1, const float* __restrict__ b1,
                    const float* __restrict__ W2, const float* __restrict__ b2,
                    const float* __restrict__ W3, const float* __restrict__ b3,
                    float* __restrict__ out)
{
    __shared__ float sp[DIM];
    __shared__ float s1[R_UNITS];
    __shared__ float s2[R_UNITS];
    const int g = blockIdx.x, tid = threadIdx.x;

    if (tid < DIM) sp[tid] = pooled[(size_t)g * DIM + tid];
    __syncthreads();

    float acc = b1[tid];
    for (int k = 0; k < DIM; k++) acc += sp[k] * W1[(size_t)k * R_UNITS + tid];
    s1[tid] = selu_f(acc);
    __syncthreads();

    acc = b2[tid];
    for (int k = 0; k < R_UNITS; k++) acc += s1[k] * W2[(size_t)k * R_UNITS + tid];
    s2[tid] = selu_f(acc) * W3[tid];
    __syncthreads();

    for (int s = 128; s > 0; s >>= 1) {
        if (tid < s) s2[tid] += s2[tid + s];
        __syncthreads();
    }
    if (tid == 0) out[g] = s2[0] + b3[0];
}

// ===========================================================================
extern "C" void kernel_launch(void* const* d_in, const int* in_sizes, int n_in,
                              void* d_out, int out_size, void* d_ws, size_t ws_size,
                              hipStream_t stream)
{
    const float* link_state = (const float*)d_in[0];
    const int*   gids       = (const int*)d_in[1];
    const int*   first      = (const int*)d_in[2];
    const int*   second     = (const int*)d_in[3];
    const float* Wmsg       = (const float*)d_in[5];
    const float* bmsg       = (const float*)d_in[6];
    const float* gK         = (const float*)d_in[7];
    const float* gU         = (const float*)d_in[8];
    const float* gbias      = (const float*)d_in[9];
    const float* W1         = (const float*)d_in[10];
    const float* b1         = (const float*)d_in[11];
    const float* W2         = (const float*)d_in[12];
    const float* b2         = (const float*)d_in[13];
    const float* W3         = (const float*)d_in[14];
    const float* b3         = (const float*)d_in[15];
    float* out = (float*)d_out;

    // ws layout (all segments 16B aligned):
    //   offsets[100004] counts[1e5] cursor[1e5] sfirst[P] ssecond[P]
    //   wt[65536 us] wb[196608 us] hb_hi[E*128 us] hb_lo[E*128 us] agg[E*128 f32]
    int* offsets = (int*)d_ws;
    int* counts  = offsets + 100004;
    int* cursor  = counts + E_NUM;
    int* sfirst  = cursor + E_NUM;
    int* ssecond = sfirst + P_NUM;
    ushort_t* wt    = (ushort_t*)(ssecond + P_NUM);
    ushort_t* wb    = wt + 65536;
    ushort_t* hb_hi = wb + 196608;
    ushort_t* hb_lo = hb_hi + (size_t)E_NUM * DIM;
    float*    agg   = (float*)(hb_lo + (size_t)E_NUM * DIM);

    const size_t agg_bytes = (size_t)E_NUM * DIM * sizeof(float);

    // ---- one-time prep ----
    hipMemsetAsync(counts, 0, E_NUM * sizeof(int), stream);
    hipMemsetAsync(cursor, 0, E_NUM * sizeof(int), stream);
    hist_kernel<<<P_NUM / 256, 256, 0, stream>>>(second, counts);
    scan_kernel<<<1, 1024, 0, stream>>>(counts, offsets);
    fill_kernel<<<P_NUM / 256, 256, 0, stream>>>(first, second, offsets, cursor,
                                                 sfirst, ssecond);
    wt_build_kernel<<<32, 256, 0, stream>>>(Wmsg, wt);
    wb_build_kernel<<<96, 256, 0, stream>>>(gK, gU, wb);
    cast_h_kernel<<<(E_NUM * DIM) / 256, 256, 0, stream>>>(link_state, hb_hi, hb_lo);

    // ---- message-passing steps ----
    for (int t = 0; t < T_STEPS; t++) {
        hipMemsetAsync(agg, 0, agg_bytes, stream);
        msg_mfma3_kernel<<<P_NUM / MT, 256, 0, stream>>>(hb_hi, hb_lo,
                                                         sfirst, ssecond,
                                                         wt, bmsg, agg);
        gru_mfma_kernel<<<E_NUM / 32, 256, 0, stream>>>(agg, hb_hi, hb_lo,
                                                        wb, gbias);
    }

    // ---- pool + readout ----
    float* pooled = agg;  // reuse
    hipMemsetAsync(pooled, 0, (size_t)G_NUM * DIM * sizeof(float), stream);
    pool_kernel<<<(E_NUM * DIM) / 256, 256, 0, stream>>>(hb_hi, hb_lo, gids, pooled);
    readout_kernel<<<G_NUM, 256, 0, stream>>>(pooled, W1, b1, W2, b2, W3, b3, out);
}

// Round 6
// 5417.741 us; speedup vs baseline: 4.7146x; 1.1224x over previous
//
#include <hip/hip_runtime.h>
#include <math.h>

#define DIM 128
#define E_NUM 100000
#define P_NUM 800000
#define G_NUM 1000
#define T_STEPS 8
#define R_UNITS 256

typedef __attribute__((ext_vector_type(8))) short bf16x8;   // 8 bf16 = 4 VGPRs
typedef __attribute__((ext_vector_type(4))) float f32x4;    // 16x16 MFMA acc

typedef unsigned short ushort_t;
typedef unsigned int   uint_t;

__device__ __forceinline__ float selu_f(float x) {
    const float alpha = 1.6732632423543772f;
    const float scale = 1.0507009873554805f;
    return x > 0.f ? scale * x : scale * alpha * expm1f(x);
}

__device__ __forceinline__ ushort_t f2bf(float x) {
    uint_t u = __float_as_uint(x);
    uint_t r = (u + 0x7fffu + ((u >> 16) & 1u)) >> 16;
    return (ushort_t)r;
}
__device__ __forceinline__ float bf2f(ushort_t h) {
    return __uint_as_float(((uint_t)h) << 16);
}

// ===========================================================================
// CSR build (once per launch; states_second fixed across steps)
// ===========================================================================
__global__ __launch_bounds__(256)
void hist_kernel(const int* __restrict__ second, int* __restrict__ counts)
{
    const int p = blockIdx.x * 256 + threadIdx.x;
    atomicAdd(&counts[second[p]], 1);
}

__global__ __launch_bounds__(1024)
void scan_kernel(const int* __restrict__ counts, int* __restrict__ offsets)
{
    __shared__ int buf[1024];
    __shared__ int carry_s;
    const int tid = threadIdx.x;
    if (tid == 0) carry_s = 0;
    __syncthreads();
    for (int base = 0; base < E_NUM; base += 1024) {
        const int i = base + tid;
        const int v = (i < E_NUM) ? counts[i] : 0;
        buf[tid] = v;
        __syncthreads();
        for (int off = 1; off < 1024; off <<= 1) {
            const int t = (tid >= off) ? buf[tid - off] : 0;
            __syncthreads();
            buf[tid] += t;
            __syncthreads();
        }
        const int carry = carry_s;
        if (i < E_NUM) offsets[i] = carry + buf[tid] - v;
        __syncthreads();
        if (tid == 0) carry_s += buf[1023];
        __syncthreads();
    }
    if (tid == 0) offsets[E_NUM] = P_NUM;
}

__global__ __launch_bounds__(256)
void fill_kernel(const int* __restrict__ first, const int* __restrict__ second,
                 const int* __restrict__ offsets, int* __restrict__ cursor,
                 int* __restrict__ sfirst, int* __restrict__ ssecond)
{
    const int p = blockIdx.x * 256 + threadIdx.x;
    const int d = second[p];
    const int pos = atomicAdd(&cursor[d], 1);
    const int idx = offsets[d] + pos;
    sfirst[idx] = first[p];
    ssecond[idx] = d;
}

// ===========================================================================
// One-time prep.
// cast_h: split-bf16 (hi+lo) of link_state.
// wt (msg weights Wmsg [256,128]), frag-packed for DIRECT GLOBAL reads:
//   wt[ks(8)][comp(2)][nt(8)][lane(64)][8 bf16]; B[k][n]:
//   n = nt*16 + (lane&15), k = ks*32 + (lane>>4)*8 + j.   (128 KB, L2-hot)
// wb (GRU weights K,U [128,384] each), same frag scheme over combined N=384:
//   wb[ks(4)][gemm(2)][comp(2)][nt(24)][lane(64)][8 bf16]  (384 KB, L2-hot)
// ===========================================================================
__global__ __launch_bounds__(256)
void cast_h_kernel(const float* __restrict__ src,
                   ushort_t* __restrict__ dhi, ushort_t* __restrict__ dlo)
{
    const int idx = blockIdx.x * 256 + threadIdx.x;
    const float x = src[idx];
    const ushort_t hi = f2bf(x);
    dhi[idx] = hi;
    dlo[idx] = f2bf(x - bf2f(hi));
}

__global__ __launch_bounds__(256)
void wt_build_kernel(const float* __restrict__ Wmsg, ushort_t* __restrict__ wt)
{
    const int idx  = blockIdx.x * 256 + threadIdx.x;   // 8192 frag-slots
    const int lane = idx & 63;
    const int nt   = (idx >> 6) & 7;
    const int comp = (idx >> 9) & 1;
    const int ks   = idx >> 10;                        // 0..7
    const int n    = nt * 16 + (lane & 15);
    const int kb   = ks * 32 + (lane >> 4) * 8;
#pragma unroll
    for (int j = 0; j < 8; j++) {
        const float w = Wmsg[(size_t)(kb + j) * DIM + n];
        const ushort_t hi = f2bf(w);
        wt[(size_t)idx * 8 + j] = comp ? f2bf(w - bf2f(hi)) : hi;
    }
}

__global__ __launch_bounds__(256)
void wb_build_kernel(const float* __restrict__ K, const float* __restrict__ U,
                     ushort_t* __restrict__ wb)
{
    const int idx  = blockIdx.x * 256 + threadIdx.x;   // 24576 frag-slots
    const int lane = idx & 63;
    int t = idx >> 6;                                  // 0..383
    const int nt   = t % 24;  t /= 24;
    const int comp = t & 1;   t >>= 1;
    const int gemm = t & 1;
    const int ks   = t >> 1;                           // 0..3
    const float* src = gemm ? U : K;
    const int n  = nt * 16 + (lane & 15);
    const int kb = ks * 32 + (lane >> 4) * 8;
#pragma unroll
    for (int j = 0; j < 8; j++) {
        const float w = src[(size_t)(kb + j) * 384 + n];
        const ushort_t hi = f2bf(w);
        wb[(size_t)idx * 8 + j] = comp ? f2bf(w - bf2f(hi)) : hi;
    }
}

// ===========================================================================
// bf16x3 MFMA message kernel. Block: 256 thr (4 waves), M=64 pairs, N=128,
// K=256 (8 k-steps of 32, FULLY UNROLLED for load/MFMA ILP). Wave w: all 4
// row-tiles x 2 n-tiles (disjoint n across waves; B direct from global wt).
// launch_bounds (256,3): VGPR cap ~170 so occupancy stays ~3 blocks/CU.
// Epilogue: bias+selu -> Ms (LDS) -> segmented sum by dst.
// ===========================================================================
#define MT 64
#define MS_STRIDE 132

__global__ __launch_bounds__(256, 3)
void msg_mfma3_kernel(const ushort_t* __restrict__ hbh, const ushort_t* __restrict__ hbl,
                      const int* __restrict__ sfirst, const int* __restrict__ ssecond,
                      const ushort_t* __restrict__ wt,
                      const float* __restrict__ bmsg, float* __restrict__ agg)
{
    __shared__ float Ms[MT * MS_STRIDE];          // 33792 B
    __shared__ int f_s[MT], s_s[MT];
    __shared__ int prevdst, nextdst;

    const int tid  = threadIdx.x;
    const int lane = tid & 63;
    const int w    = tid >> 6;
    const int p0   = blockIdx.x * MT;

    if (tid < MT) {
        f_s[tid] = sfirst[p0 + tid];
        s_s[tid] = ssecond[p0 + tid];
    }
    if (tid == 64) prevdst = (p0 == 0) ? -1 : ssecond[p0 - 1];
    if (tid == 65) nextdst = (p0 + MT >= P_NUM) ? -1 : ssecond[p0 + MT];
    __syncthreads();

    const int m16  = lane & 15;
    const int quad = lane >> 4;

    int rf[4], rs[4];
#pragma unroll
    for (int rt = 0; rt < 4; rt++) {
        rf[rt] = f_s[rt * 16 + m16];
        rs[rt] = s_s[rt * 16 + m16];
    }

    f32x4 acc[4][2];
#pragma unroll
    for (int rt = 0; rt < 4; rt++)
#pragma unroll
        for (int ntl = 0; ntl < 2; ntl++) acc[rt][ntl] = {};

#pragma unroll
    for (int ks = 0; ks < 8; ks++) {
        const int kg  = ks * 32 + quad * 8;        // k-step never straddles 128
        const bool use_f = (kg < DIM);             // compile-time per unrolled ks
        const int off = kg & (DIM - 1);
        bf16x8 ah[4], al[4];
#pragma unroll
        for (int rt = 0; rt < 4; rt++) {
            const int row = use_f ? rf[rt] : rs[rt];
            ah[rt] = *(const bf16x8*)(hbh + (size_t)row * DIM + off);
            al[rt] = *(const bf16x8*)(hbl + (size_t)row * DIM + off);
        }
#pragma unroll
        for (int ntl = 0; ntl < 2; ntl++) {
            const int nt = w * 2 + ntl;
            const bf16x8 bh = *(const bf16x8*)(wt + (size_t)(((ks * 2 + 0) * 8 + nt) * 64 + lane) * 8);
            const bf16x8 bl = *(const bf16x8*)(wt + (size_t)(((ks * 2 + 1) * 8 + nt) * 64 + lane) * 8);
#pragma unroll
            for (int rt = 0; rt < 4; rt++) {
                acc[rt][ntl] = __builtin_amdgcn_mfma_f32_16x16x32_bf16(ah[rt], bh, acc[rt][ntl], 0, 0, 0);
                acc[rt][ntl] = __builtin_amdgcn_mfma_f32_16x16x32_bf16(al[rt], bh, acc[rt][ntl], 0, 0, 0);
                acc[rt][ntl] = __builtin_amdgcn_mfma_f32_16x16x32_bf16(ah[rt], bl, acc[rt][ntl], 0, 0, 0);
            }
        }
    }

    // ---- epilogue: bias + selu into Ms (C layout: col=lane&15, row=quad*4+reg) ----
#pragma unroll
    for (int ntl = 0; ntl < 2; ntl++) {
        const int c = (w * 2 + ntl) * 16 + m16;
        const float bb = bmsg[c];
#pragma unroll
        for (int rt = 0; rt < 4; rt++) {
#pragma unroll
            for (int reg = 0; reg < 4; reg++) {
                const int row = rt * 16 + quad * 4 + reg;
                Ms[row * MS_STRIDE + c] = selu_f(acc[rt][ntl][reg] + bb);
            }
        }
    }
    __syncthreads();

    // ---- segmented reduction by destination ----
    const int r  = tid & 63;
    const int cg = tid >> 6;
    const int d  = s_s[r];
    const bool leader = (r == 0) || (d != s_s[r - 1]);
    if (leader) {
        int end = r + 1;
        while (end < MT && s_s[end] == d) end++;
        const bool needs_atomic = (r == 0 && d == prevdst) ||
                                  (end == MT && d == nextdst);
        float sacc[32];
#pragma unroll
        for (int c = 0; c < 32; c++) sacc[c] = 0.f;
        for (int rr = r; rr < end; rr++) {
            const float* mrow = Ms + rr * MS_STRIDE + cg * 32;
#pragma unroll
            for (int c = 0; c < 32; c++) sacc[c] += mrow[c];
        }
        float* dst = agg + (size_t)d * DIM + cg * 32;
        if (needs_atomic) {
#pragma unroll
            for (int c = 0; c < 32; c++) atomicAdd(dst + c, sacc[c]);
        } else {
#pragma unroll
            for (int c4 = 0; c4 < 8; c4++) {
                float4 v = make_float4(sacc[c4 * 4], sacc[c4 * 4 + 1],
                                       sacc[c4 * 4 + 2], sacc[c4 * 4 + 3]);
                *(float4*)(dst + c4 * 4) = v;
            }
        }
    }
}

// ===========================================================================
// bf16x3 MFMA GRU kernel. Block: 256 thr (4 waves), M=32 edges. Combined
// N=384 (z|r|h); wave w owns n-tiles w*6..w*6+5 of BOTH gemms. K=128,
// 4 k-steps FULLY UNROLLED (LDS caps occupancy at 2 blocks/CU, so VGPR up
// to 256 is free -> launch_bounds (256,2)).
// ===========================================================================
#define EXS 132

__global__ __launch_bounds__(256, 2)
void gru_mfma_kernel(const float* __restrict__ agg,
                     ushort_t* __restrict__ hbh, ushort_t* __restrict__ hbl,
                     const ushort_t* __restrict__ wb,
                     const float* __restrict__ bias)
{
    __shared__ float ex[4 * 32 * EXS];            // 67584 B
    const int tid  = threadIdx.x;
    const int lane = tid & 63;
    const int w    = tid >> 6;
    const int e0   = blockIdx.x * 32;
    const int m16  = lane & 15;
    const int quad = lane >> 4;

    f32x4 ax[2][6], ah[2][6];
#pragma unroll
    for (int rt = 0; rt < 2; rt++)
#pragma unroll
        for (int n = 0; n < 6; n++) { ax[rt][n] = {}; ah[rt][n] = {}; }

#pragma unroll
    for (int ks = 0; ks < 4; ks++) {
        const int koff = ks * 32 + quad * 8;
        bf16x8 xh_[2], xl_[2], hh_[2], hl_[2];
#pragma unroll
        for (int rt = 0; rt < 2; rt++) {
            const size_t grow = (size_t)(e0 + rt * 16 + m16);
            const float* xp = agg + grow * DIM + koff;
            const float4 v0 = *(const float4*)xp;
            const float4 v1 = *(const float4*)(xp + 4);
            float xv[8] = {v0.x, v0.y, v0.z, v0.w, v1.x, v1.y, v1.z, v1.w};
            bf16x8 xh_t, xl_t;
#pragma unroll
            for (int j = 0; j < 8; j++) {
                const ushort_t hi = f2bf(xv[j]);
                xh_t[j] = (short)hi;
                xl_t[j] = (short)f2bf(xv[j] - bf2f(hi));
            }
            xh_[rt] = xh_t;
            xl_[rt] = xl_t;
            hh_[rt] = *(const bf16x8*)(hbh + grow * DIM + koff);
            hl_[rt] = *(const bf16x8*)(hbl + grow * DIM + koff);
        }
#pragma unroll
        for (int ntl = 0; ntl < 6; ntl++) {
            const int nt = w * 6 + ntl;
            const size_t base = (size_t)(ks * 2) * 2 * 24;   // [ks][gemm][comp]
            const bf16x8 bKh = *(const bf16x8*)(wb + (((base + 0 * 24) + nt) * 64 + lane) * 8);
            const bf16x8 bKl = *(const bf16x8*)(wb + (((base + 1 * 24) + nt) * 64 + lane) * 8);
            const bf16x8 bUh = *(const bf16x8*)(wb + (((base + 2 * 24) + nt) * 64 + lane) * 8);
            const bf16x8 bUl = *(const bf16x8*)(wb + (((base + 3 * 24) + nt) * 64 + lane) * 8);
#pragma unroll
            for (int rt = 0; rt < 2; rt++) {
                ax[rt][ntl] = __builtin_amdgcn_mfma_f32_16x16x32_bf16(xh_[rt], bKh, ax[rt][ntl], 0, 0, 0);
                ax[rt][ntl] = __builtin_amdgcn_mfma_f32_16x16x32_bf16(xl_[rt], bKh, ax[rt][ntl], 0, 0, 0);
                ax[rt][ntl] = __builtin_amdgcn_mfma_f32_16x16x32_bf16(xh_[rt], bKl, ax[rt][ntl], 0, 0, 0);
                ah[rt][ntl] = __builtin_amdgcn_mfma_f32_16x16x32_bf16(hh_[rt], bUh, ah[rt][ntl], 0, 0, 0);
                ah[rt][ntl] = __builtin_amdgcn_mfma_f32_16x16x32_bf16(hl_[rt], bUh, ah[rt][ntl], 0, 0, 0);
                ah[rt][ntl] = __builtin_amdgcn_mfma_f32_16x16x32_bf16(hh_[rt], bUl, ah[rt][ntl], 0, 0, 0);
            }
        }
    }

    // ---- exchange: planes 0=z-sum, 1=r-sum, 2=xh, 3=rh ----
#pragma unroll
    for (int ntl = 0; ntl < 6; ntl++) {
        const int cglob = (w * 6 + ntl) * 16 + m16;     // 0..383
        const int gb = cglob >> 7;                       // 0=z 1=r 2=h
        const int cb = cglob & 127;
        const float b0v = bias[cglob];
        const float b1v = bias[384 + cglob];
#pragma unroll
        for (int rt = 0; rt < 2; rt++) {
#pragma unroll
            for (int reg = 0; reg < 4; reg++) {
                const int row = rt * 16 + quad * 4 + reg;
                const float mx = ax[rt][ntl][reg] + b0v;
                const float mh = ah[rt][ntl][reg] + b1v;
                if (gb == 0)      ex[0 * 32 * EXS + row * EXS + cb] = mx + mh;
                else if (gb == 1) ex[1 * 32 * EXS + row * EXS + cb] = mx + mh;
                else {
                    ex[2 * 32 * EXS + row * EXS + cb] = mx;
                    ex[3 * 32 * EXS + row * EXS + cb] = mh;
                }
            }
        }
    }
    __syncthreads();

    // ---- gates: thread t -> row t>>3, cols (t&7)*16 .. +15 ----
    const int row = tid >> 3;
    const int c0  = (tid & 7) * 16;
    const size_t gbase = (size_t)(e0 + row) * DIM;
#pragma unroll
    for (int j = 0; j < 16; j++) {
        const int c = c0 + j;
        const float sz = ex[0 * 32 * EXS + row * EXS + c];
        const float sr = ex[1 * 32 * EXS + row * EXS + c];
        const float xh = ex[2 * 32 * EXS + row * EXS + c];
        const float rh = ex[3 * 32 * EXS + row * EXS + c];
        const float z  = 1.f / (1.f + expf(-sz));
        const float r  = 1.f / (1.f + expf(-sr));
        const float hc = tanhf(xh + r * rh);
        const size_t g = gbase + c;
        const float hp = bf2f(hbh[g]) + bf2f(hbl[g]);
        const float hn = z * hp + (1.f - z) * hc;
        const ushort_t hi = f2bf(hn);
        hbh[g] = hi;
        hbl[g] = f2bf(hn - bf2f(hi));
    }
}

// ===========================================================================
// Graph pooling + readout
// ===========================================================================
__global__ __launch_bounds__(256)
void pool_kernel(const ushort_t* __restrict__ hbh, const ushort_t* __restrict__ hbl,
                 const int* __restrict__ gid, float* __restrict__ pooled)
{
    const int idx = blockIdx.x * 256 + threadIdx.x;
    const int e = idx >> 7;
    const int n = idx & 127;
    const float hv = bf2f(hbh[idx]) + bf2f(hbl[idx]);
    atomicAdd(pooled + (size_t)gid[e] * DIM + n, hv);
}

__global__ __launch_bounds__(256)
void readout_kernel(const float* __restrict__ pooled,
                    const float* __restrict__ W1, const float* __restrict__ b1,
                    const float* __restrict__ W2, const float* __restrict__ b2,
                    const float* __restrict__ W3, const float* __restrict__ b3,
                    float* __restrict__ out)
{
    __shared__ float sp[DIM];
    __shared__ float s1[R_UNITS];
    __shared__ float s2[R_UNITS];
    const int g = blockIdx.x, tid = threadIdx.x;

    if (tid < DIM) sp[tid] = pooled[(size_t)g * DIM + tid];
    __syncthreads();

    float acc = b1[tid];
    for (int k = 0; k < DIM; k++) acc += sp[k] * W1[(size_t)k * R_UNITS + tid];
    s1[tid] = selu_f(acc);
    __syncthreads();

    acc = b2[tid];
    for (int k = 0; k < R_UNITS; k++) acc += s1[k] * W2[(size_t)k * R_UNITS + tid];
    s2[tid] = selu_f(acc) * W3[tid];
    __syncthreads();

    for (int s = 128; s > 0; s >>= 1) {
        if (tid < s) s2[tid] += s2[tid + s];
        __syncthreads();
    }
    if (tid == 0) out[g] = s2[0] + b3[0];
}

// ===========================================================================
extern "C" void kernel_launch(void* const* d_in, const int* in_sizes, int n_in,
                              void* d_out, int out_size, void* d_ws, size_t ws_size,
                              hipStream_t stream)
{
    const float* link_state = (const float*)d_in[0];
    const int*   gids       = (const int*)d_in[1];
    const int*   first      = (const int*)d_in[2];
    const int*   second     = (const int*)d_in[3];
    const float* Wmsg       = (const float*)d_in[5];
    const float* bmsg       = (const float*)d_in[6];
    const float* gK         = (const float*)d_in[7];
    const float* gU         = (const float*)d_in[8];
    const float* gbias      = (const float*)d_in[9];
    const float* W1         = (const float*)d_in[10];
    const float* b1         = (const float*)d_in[11];
    const float* W2         = (const float*)d_in[12];
    const float* b2         = (const float*)d_in[13];
    const float* W3         = (const float*)d_in[14];
    const float* b3         = (const float*)d_in[15];
    float* out = (float*)d_out;

    // ws layout (all segments 16B aligned):
    //   offsets[100004] counts[1e5] cursor[1e5] sfirst[P] ssecond[P]
    //   wt[65536 us] wb[196608 us] hb_hi[E*128 us] hb_lo[E*128 us] agg[E*128 f32]
    int* offsets = (int*)d_ws;
    int* counts  = offsets + 100004;
    int* cursor  = counts + E_NUM;
    int* sfirst  = cursor + E_NUM;
    int* ssecond = sfirst + P_NUM;
    ushort_t* wt    = (ushort_t*)(ssecond + P_NUM);
    ushort_t* wb    = wt + 65536;
    ushort_t* hb_hi = wb + 196608;
    ushort_t* hb_lo = hb_hi + (size_t)E_NUM * DIM;
    float*    agg   = (float*)(hb_lo + (size_t)E_NUM * DIM);

    const size_t agg_bytes = (size_t)E_NUM * DIM * sizeof(float);

    // ---- one-time prep ----
    hipMemsetAsync(counts, 0, E_NUM * sizeof(int), stream);
    hipMemsetAsync(cursor, 0, E_NUM * sizeof(int), stream);
    hist_kernel<<<P_NUM / 256, 256, 0, stream>>>(second, counts);
    scan_kernel<<<1, 1024, 0, stream>>>(counts, offsets);
    fill_kernel<<<P_NUM / 256, 256, 0, stream>>>(first, second, offsets, cursor,
                                                 sfirst, ssecond);
    wt_build_kernel<<<32, 256, 0, stream>>>(Wmsg, wt);
    wb_build_kernel<<<96, 256, 0, stream>>>(gK, gU, wb);
    cast_h_kernel<<<(E_NUM * DIM) / 256, 256, 0, stream>>>(link_state, hb_hi, hb_lo);

    // ---- message-passing steps ----
    for (int t = 0; t < T_STEPS; t++) {
        hipMemsetAsync(agg, 0, agg_bytes, stream);
        msg_mfma3_kernel<<<P_NUM / MT, 256, 0, stream>>>(hb_hi, hb_lo,
                                                         sfirst, ssecond,
                                                         wt, bmsg, agg);
        gru_mfma_kernel<<<E_NUM / 32, 256, 0, stream>>>(agg, hb_hi, hb_lo,
                                                        wb, gbias);
    }

    // ---- pool + readout ----
    float* pooled = agg;  // reuse
    hipMemsetAsync(pooled, 0, (size_t)G_NUM * DIM * sizeof(float), stream);
    pool_kernel<<<(E_NUM * DIM) / 256, 256, 0, stream>>>(hb_hi, hb_lo, gids, pooled);
    readout_kernel<<<G_NUM, 256, 0, stream>>>(pooled, W1, b1, W2, b2, W3, b3, out);
}